// Round 8
// baseline (380.351 us; speedup 1.0000x reference)
//
#include <hip/hip_runtime.h>
#include <hip/hip_bf16.h>

#define IN_DIM  128
#define OUT_DIM 64
#define SCAN_CHUNK 1024   // 256 threads x 4 elems

// ---------------------------------------------------------------------------
// Prologue: degree histogram (also records per-edge rank) -> exclusive scan
// ---------------------------------------------------------------------------
__global__ void k_zero(unsigned* __restrict__ p, int n) {
    int i = blockIdx.x * blockDim.x + threadIdx.x;
    if (i < n) p[i] = 0u;
}

// rank[e] = number of earlier edges with same dst (atomic order; any perm ok)
__global__ void k_hist2(const int* __restrict__ dst, unsigned* __restrict__ cnt,
                        unsigned short* __restrict__ rank, int nE) {
    int e = blockIdx.x * blockDim.x + threadIdx.x;
    if (e < nE) {
        unsigned k = atomicAdd(&cnt[dst[e]], 1u);
        rank[e] = (unsigned short)k;       // sequential write
    }
}

__global__ __launch_bounds__(256) void k_scanA(const unsigned* __restrict__ cnt,
                                               unsigned* __restrict__ offs,
                                               unsigned* __restrict__ partials,
                                               float* __restrict__ dinv, int n) {
    __shared__ unsigned sums[256];
    int base = blockIdx.x * SCAN_CHUNK + threadIdx.x * 4;
    unsigned v[4]; unsigned s = 0;
#pragma unroll
    for (int k = 0; k < 4; ++k) {
        int i = base + k;
        unsigned c = (i < n) ? cnt[i] : 0u;
        if (i < n) dinv[i] = rsqrtf((float)c + 1.0f);   // +1 self-loop
        v[k] = s; s += c;
    }
    sums[threadIdx.x] = s;
    __syncthreads();
    for (int d = 1; d < 256; d <<= 1) {
        unsigned t = (threadIdx.x >= (unsigned)d) ? sums[threadIdx.x - d] : 0u;
        __syncthreads();
        sums[threadIdx.x] += t;
        __syncthreads();
    }
    unsigned excl = sums[threadIdx.x] - s;
#pragma unroll
    for (int k = 0; k < 4; ++k) {
        int i = base + k;
        if (i < n) offs[i] = excl + v[k];
    }
    if (threadIdx.x == 255) partials[blockIdx.x] = sums[255];
}

__global__ void k_scanB(unsigned* __restrict__ partials, int nb) {
    __shared__ unsigned s[256];
    unsigned v = (threadIdx.x < (unsigned)nb) ? partials[threadIdx.x] : 0u;
    s[threadIdx.x] = v;
    __syncthreads();
    for (int d = 1; d < 256; d <<= 1) {
        unsigned t = (threadIdx.x >= (unsigned)d) ? s[threadIdx.x - d] : 0u;
        __syncthreads();
        s[threadIdx.x] += t;
        __syncthreads();
    }
    if (threadIdx.x < (unsigned)nb) partials[threadIdx.x] = s[threadIdx.x] - v;
}

__global__ void k_scanC(unsigned* __restrict__ offs, const unsigned* __restrict__ partials,
                        int n) {
    int i = blockIdx.x * blockDim.x + threadIdx.x;
    if (i < n) offs[i] += partials[i / SCAN_CHUNK];
}

// ---------------------------------------------------------------------------
// Linear tile body (512 threads, 32 rows, 4 rows/wave). W + x-tile in LDS;
// compute reads are LDS broadcasts. RELU folds relu(dinv*in) into staging.
// ---------------------------------------------------------------------------
template <int KD, bool RELU>
__device__ __forceinline__ void lin_body(const float* __restrict__ in,
                                         const float* __restrict__ W,
                                         const float* __restrict__ dinv,
                                         float* __restrict__ outp,
                                         int n, int tile,
                                         float* __restrict__ Wl,
                                         float* __restrict__ xs, int tid) {
    for (int i = tid; i < KD * 16; i += 512)
        ((float4*)Wl)[i] = ((const float4*)W)[i];

    int r0t = tile * 32;
    const int F4 = 32 * KD / 4;
    const float4* gin = (const float4*)(in + (size_t)r0t * KD);
    for (int f = tid; f < F4; f += 512) {
        int row = r0t + f / (KD / 4);
        float4 v = {0.f, 0.f, 0.f, 0.f};
        if (row < n) {
            v = gin[f];                  // coalesced
            if (RELU) {
                float dv = dinv[row];
                v.x = fmaxf(dv * v.x, 0.f); v.y = fmaxf(dv * v.y, 0.f);
                v.z = fmaxf(dv * v.z, 0.f); v.w = fmaxf(dv * v.w, 0.f);
            }
        }
        ((float4*)xs)[f] = v;
    }
    __syncthreads();

    int wid = tid >> 6, lane = tid & 63;
    int r0 = wid * 4;                    // 4 rows per wave
    float acc[4] = {0.f, 0.f, 0.f, 0.f};
#pragma unroll 8
    for (int k4 = 0; k4 < KD / 4; ++k4) {
        float w0 = Wl[(4 * k4 + 0) * 64 + lane];
        float w1 = Wl[(4 * k4 + 1) * 64 + lane];
        float w2 = Wl[(4 * k4 + 2) * 64 + lane];
        float w3 = Wl[(4 * k4 + 3) * 64 + lane];
#pragma unroll
        for (int r = 0; r < 4; ++r) {
            float4 xv = *(const float4*)&xs[(r0 + r) * KD + 4 * k4];  // LDS broadcast
            acc[r] += xv.x * w0 + xv.y * w1 + xv.z * w2 + xv.w * w3;
        }
    }
#pragma unroll
    for (int r = 0; r < 4; ++r) {
        int row = r0t + r0 + r;
        if (row < n) outp[(size_t)row * 64 + lane] = dinv[row] * acc[r];
    }
}

// ---------------------------------------------------------------------------
// Mega kernel: {layer-1 linear tiles} + {atomic-free edge scatter} interleaved
// (independent work; scat's memory-latency stalls hide under lin's VALU).
// ---------------------------------------------------------------------------
__global__ __launch_bounds__(512) void k_mega(const float* __restrict__ x,
                                              const float* __restrict__ W,
                                              const float* __restrict__ dinv,
                                              float* __restrict__ hs, int n,
                                              const int* __restrict__ src,
                                              const int* __restrict__ dst,
                                              const unsigned short* __restrict__ rank,
                                              const unsigned* __restrict__ offs,
                                              int* __restrict__ perm, int nE) {
    __shared__ float Wl[IN_DIM * 64];    // 32 KiB
    __shared__ float xs[32 * IN_DIM];    // 16 KiB
    int nL = (n + 31) / 32;
    int nS = (nE + 511) / 512;
    long tot = nL + nS;
    long b = blockIdx.x;
    int lo = (int)((b * nL) / tot);
    int hi = (int)(((b + 1) * nL) / tot);
    if (hi > lo) {
        lin_body<IN_DIM, false>(x, W, dinv, hs, n, lo, Wl, xs, threadIdx.x);
    } else {
        int e = (int)(b - lo) * 512 + threadIdx.x;
        if (e < nE) {
            unsigned p = offs[dst[e]] + (unsigned)rank[e];
            __builtin_nontemporal_store(src[e], &perm[p]);
        }
    }
}

// Standalone linear (layer 2)
template <int KD, bool RELU>
__global__ __launch_bounds__(512) void k_lin(const float* __restrict__ in,
                                             const float* __restrict__ W,
                                             const float* __restrict__ dinv,
                                             float* __restrict__ outp, int n) {
    __shared__ float Wl[KD * 64];
    __shared__ float xs[32 * KD];
    lin_body<KD, RELU>(in, W, dinv, outp, n, blockIdx.x, Wl, xs, threadIdx.x);
}

// ---------------------------------------------------------------------------
// CSR gather, 8-way ILP: one wave per node, lane = feature dim.
// acc = hs[r] (self-loop) + sum over neighbors; FIN applies final dinv[r].
// ---------------------------------------------------------------------------
template <bool FIN>
__global__ __launch_bounds__(256) void k_gather(const float* __restrict__ hs,
                                                const unsigned* __restrict__ offs,
                                                const int* __restrict__ perm,
                                                const float* __restrict__ dinv,
                                                float* __restrict__ outb,
                                                int n, int nE) {
    int lane = threadIdx.x & 63;
    int r = blockIdx.x * 4 + (threadIdx.x >> 6);
    if (r >= n) return;
    unsigned beg = offs[r];
    unsigned end = (r + 1 < n) ? offs[r + 1] : (unsigned)nE;
    float a0 = hs[(size_t)r * 64 + lane];            // self-loop term
    float a1 = 0.f, a2 = 0.f, a3 = 0.f, a4 = 0.f, a5 = 0.f, a6 = 0.f, a7 = 0.f;
    for (unsigned e0 = beg; e0 < end; e0 += 64) {
        unsigned c = min(64u, end - e0);
        int sl = (lane < (int)c) ? perm[e0 + lane] : 0;   // coalesced edge read
        unsigned k = 0;
        for (; k + 8 <= c; k += 8) {
            int s0 = __shfl(sl, (int)k);
            int s1 = __shfl(sl, (int)k + 1);
            int s2 = __shfl(sl, (int)k + 2);
            int s3 = __shfl(sl, (int)k + 3);
            int s4 = __shfl(sl, (int)k + 4);
            int s5 = __shfl(sl, (int)k + 5);
            int s6 = __shfl(sl, (int)k + 6);
            int s7 = __shfl(sl, (int)k + 7);
            float v0 = hs[(size_t)s0 * 64 + lane];
            float v1 = hs[(size_t)s1 * 64 + lane];
            float v2 = hs[(size_t)s2 * 64 + lane];
            float v3 = hs[(size_t)s3 * 64 + lane];
            float v4 = hs[(size_t)s4 * 64 + lane];
            float v5 = hs[(size_t)s5 * 64 + lane];
            float v6 = hs[(size_t)s6 * 64 + lane];
            float v7 = hs[(size_t)s7 * 64 + lane];
            a0 += v0; a1 += v1; a2 += v2; a3 += v3;
            a4 += v4; a5 += v5; a6 += v6; a7 += v7;
        }
        for (; k + 4 <= c; k += 4) {
            int s0 = __shfl(sl, (int)k);
            int s1 = __shfl(sl, (int)k + 1);
            int s2 = __shfl(sl, (int)k + 2);
            int s3 = __shfl(sl, (int)k + 3);
            float v0 = hs[(size_t)s0 * 64 + lane];
            float v1 = hs[(size_t)s1 * 64 + lane];
            float v2 = hs[(size_t)s2 * 64 + lane];
            float v3 = hs[(size_t)s3 * 64 + lane];
            a0 += v0; a1 += v1; a2 += v2; a3 += v3;
        }
        for (; k < c; ++k) {
            int s = __shfl(sl, (int)k);
            a0 += hs[(size_t)s * 64 + lane];
        }
    }
    float acc = ((a0 + a1) + (a2 + a3)) + ((a4 + a5) + (a6 + a7));
    if (FIN) acc *= dinv[r];
    outb[(size_t)r * 64 + lane] = acc;
}

// ---------------------------------------------------------------------------
extern "C" void kernel_launch(void* const* d_in, const int* in_sizes, int n_in,
                              void* d_out, int out_size, void* d_ws, size_t ws_size,
                              hipStream_t stream) {
    const float* x  = (const float*)d_in[0];
    const int*   ei = (const int*)d_in[1];
    const float* W1 = (const float*)d_in[2];
    const float* W2 = (const float*)d_in[3];
    float* out = (float*)d_out;

    int n  = in_sizes[0] / IN_DIM;   // 100000
    int nE = in_sizes[1] / 2;        // 1600000
    const int* src = ei;
    const int* dst = ei + nE;

    // workspace carve-up (256B-aligned); d_out doubles as the layer-1 agg buffer
    char* w = (char*)d_ws;
    size_t nAl = ((size_t)n * 4 + 255) & ~(size_t)255;
    float*          dinv     = (float*)w;          w += nAl;
    unsigned*       cnt      = (unsigned*)w;       w += nAl;
    unsigned*       offs     = (unsigned*)w;       w += nAl;
    unsigned*       partials = (unsigned*)w;       w += 4096;
    unsigned short* rank     = (unsigned short*)w; w += ((size_t)nE * 2 + 255) & ~(size_t)255;
    int*            perm     = (int*)w;            w += ((size_t)nE * 4 + 255) & ~(size_t)255;
    float*          hs       = (float*)w;          w += (size_t)n * 64 * 4;
    float*          agg      = out;                // layer-1 aggregate lives in d_out

    int nb    = (n + SCAN_CHUNK - 1) / SCAN_CHUNK;
    int gE    = (nE + 255) / 256;
    int gN    = (n + 255) / 256;
    int gRow  = (n + 3) / 4;
    int gTile = (n + 31) / 32;
    int nS    = (nE + 511) / 512;

    // --- prologue: degrees + per-edge ranks, node offsets ---
    k_zero<<<gN, 256, 0, stream>>>(cnt, n);
    k_hist2<<<gE, 256, 0, stream>>>(dst, cnt, rank, nE);
    k_scanA<<<nb, 256, 0, stream>>>(cnt, offs, partials, dinv, n);
    k_scanB<<<1, 256, 0, stream>>>(partials, nb);
    k_scanC<<<gN, 256, 0, stream>>>(offs, partials, n);

    // --- layer 1: fused linear + scatter, then gather ---
    k_mega<<<gTile + nS, 512, 0, stream>>>(x, W1, dinv, hs, n, src, dst, rank, offs, perm, nE);
    k_gather<false><<<gRow, 256, 0, stream>>>(hs, offs, perm, dinv, agg, n, nE);

    // --- layer 2 (reuse hs for hs2; final dinv folded into gather) ---
    k_lin<OUT_DIM, true><<<gTile, 512, 0, stream>>>(agg, W2, dinv, hs, n);
    k_gather<true><<<gRow, 256, 0, stream>>>(hs, offs, perm, dinv, out, n, nE);
}

// Round 9
// 347.734 us; speedup vs baseline: 1.0938x; 1.0938x over previous
//
#include <hip/hip_runtime.h>
#include <hip/hip_bf16.h>

#define IN_DIM  128
#define OUT_DIM 64
#define SCAN_CHUNK 1024   // 256 threads x 4 elems

// ---------------------------------------------------------------------------
// Prologue: degree histogram (also records per-edge rank) -> exclusive scan
// ---------------------------------------------------------------------------
__global__ void k_zero(unsigned* __restrict__ p, int n) {
    int i = blockIdx.x * blockDim.x + threadIdx.x;
    if (i < n) p[i] = 0u;
}

// rank[e] = number of earlier edges with same dst (atomic order; any perm ok)
__global__ void k_hist2(const int* __restrict__ dst, unsigned* __restrict__ cnt,
                        unsigned short* __restrict__ rank, int nE) {
    int e = blockIdx.x * blockDim.x + threadIdx.x;
    if (e < nE) {
        unsigned k = atomicAdd(&cnt[dst[e]], 1u);
        rank[e] = (unsigned short)k;       // sequential write
    }
}

__global__ __launch_bounds__(256) void k_scanA(const unsigned* __restrict__ cnt,
                                               unsigned* __restrict__ offs,
                                               unsigned* __restrict__ partials,
                                               float* __restrict__ dinv, int n) {
    __shared__ unsigned sums[256];
    int base = blockIdx.x * SCAN_CHUNK + threadIdx.x * 4;
    unsigned v[4]; unsigned s = 0;
#pragma unroll
    for (int k = 0; k < 4; ++k) {
        int i = base + k;
        unsigned c = (i < n) ? cnt[i] : 0u;
        if (i < n) dinv[i] = rsqrtf((float)c + 1.0f);   // +1 self-loop
        v[k] = s; s += c;
    }
    sums[threadIdx.x] = s;
    __syncthreads();
    for (int d = 1; d < 256; d <<= 1) {
        unsigned t = (threadIdx.x >= (unsigned)d) ? sums[threadIdx.x - d] : 0u;
        __syncthreads();
        sums[threadIdx.x] += t;
        __syncthreads();
    }
    unsigned excl = sums[threadIdx.x] - s;
#pragma unroll
    for (int k = 0; k < 4; ++k) {
        int i = base + k;
        if (i < n) offs[i] = excl + v[k];
    }
    if (threadIdx.x == 255) partials[blockIdx.x] = sums[255];
}

__global__ void k_scanB(unsigned* __restrict__ partials, int nb) {
    __shared__ unsigned s[256];
    unsigned v = (threadIdx.x < (unsigned)nb) ? partials[threadIdx.x] : 0u;
    s[threadIdx.x] = v;
    __syncthreads();
    for (int d = 1; d < 256; d <<= 1) {
        unsigned t = (threadIdx.x >= (unsigned)d) ? s[threadIdx.x - d] : 0u;
        __syncthreads();
        s[threadIdx.x] += t;
        __syncthreads();
    }
    if (threadIdx.x < (unsigned)nb) partials[threadIdx.x] = s[threadIdx.x] - v;
}

__global__ void k_scanC(unsigned* __restrict__ offs, const unsigned* __restrict__ partials,
                        int n) {
    int i = blockIdx.x * blockDim.x + threadIdx.x;
    if (i < n) offs[i] += partials[i / SCAN_CHUNK];
}

// ---------------------------------------------------------------------------
// Atomic-free edge scatter (LDS-free, high occupancy hides write latency)
// ---------------------------------------------------------------------------
__global__ void k_scat(const int* __restrict__ src, const int* __restrict__ dst,
                       const unsigned short* __restrict__ rank,
                       const unsigned* __restrict__ offs,
                       int* __restrict__ perm, int nE) {
    int e = blockIdx.x * blockDim.x + threadIdx.x;
    if (e < nE) {
        unsigned p = offs[dst[e]] + (unsigned)rank[e];
        __builtin_nontemporal_store(src[e], &perm[p]);
    }
}

// ---------------------------------------------------------------------------
// Linear layer, LDS-staged, 512 threads / 32-row tile / 4 rows per wave.
// lin1 (KD=128): 48 KiB LDS -> 3 blocks/CU x 8 waves = 24 waves/CU (75%).
// lin2 (KD=64):  24 KiB LDS -> 4 blocks/CU = 32 waves/CU (100%).
// W + x-tile in LDS; compute reads are LDS broadcasts.
// RELU: relu(dinv*in) folded into staging (layer-2 input).
// ---------------------------------------------------------------------------
template <int KD, bool RELU>
__global__ __launch_bounds__(512) void k_lin(const float* __restrict__ in,
                                             const float* __restrict__ W,
                                             const float* __restrict__ dinv,
                                             float* __restrict__ outp, int n) {
    __shared__ float Wl[KD * 64];        // 32 KiB (KD=128) / 16 KiB (KD=64)
    __shared__ float xs[32 * KD];        // 16 KiB / 8 KiB
    for (int i = threadIdx.x; i < KD * 16; i += 512)
        ((float4*)Wl)[i] = ((const float4*)W)[i];

    int r0t = blockIdx.x * 32;
    const int F4 = 32 * KD / 4;
    const float4* gin = (const float4*)(in + (size_t)r0t * KD);
    for (int f = threadIdx.x; f < F4; f += 512) {
        int row = r0t + f / (KD / 4);
        float4 v = {0.f, 0.f, 0.f, 0.f};
        if (row < n) {
            v = gin[f];                  // coalesced: lanes -> consecutive 16B
            if (RELU) {
                float dv = dinv[row];
                v.x = fmaxf(dv * v.x, 0.f); v.y = fmaxf(dv * v.y, 0.f);
                v.z = fmaxf(dv * v.z, 0.f); v.w = fmaxf(dv * v.w, 0.f);
            }
        }
        ((float4*)xs)[f] = v;
    }
    __syncthreads();

    int wid = threadIdx.x >> 6, lane = threadIdx.x & 63;
    int r0 = wid * 4;                    // 4 rows per wave
    float acc[4] = {0.f, 0.f, 0.f, 0.f};
#pragma unroll 8
    for (int k4 = 0; k4 < KD / 4; ++k4) {
        float w0 = Wl[(4 * k4 + 0) * 64 + lane];
        float w1 = Wl[(4 * k4 + 1) * 64 + lane];
        float w2 = Wl[(4 * k4 + 2) * 64 + lane];
        float w3 = Wl[(4 * k4 + 3) * 64 + lane];
#pragma unroll
        for (int r = 0; r < 4; ++r) {
            float4 xv = *(const float4*)&xs[(r0 + r) * KD + 4 * k4];  // LDS broadcast
            acc[r] += xv.x * w0 + xv.y * w1 + xv.z * w2 + xv.w * w3;
        }
    }
#pragma unroll
    for (int r = 0; r < 4; ++r) {
        int row = r0t + r0 + r;
        if (row < n) outp[(size_t)row * 64 + lane] = dinv[row] * acc[r];
    }
}

// ---------------------------------------------------------------------------
// CSR gather, 8-way ILP: one wave per node, lane = feature dim.
// acc = hs[r] (self-loop) + sum over neighbors; FIN applies final dinv[r].
// ---------------------------------------------------------------------------
template <bool FIN>
__global__ __launch_bounds__(256) void k_gather(const float* __restrict__ hs,
                                                const unsigned* __restrict__ offs,
                                                const int* __restrict__ perm,
                                                const float* __restrict__ dinv,
                                                float* __restrict__ outb,
                                                int n, int nE) {
    int lane = threadIdx.x & 63;
    int r = blockIdx.x * 4 + (threadIdx.x >> 6);
    if (r >= n) return;
    unsigned beg = offs[r];
    unsigned end = (r + 1 < n) ? offs[r + 1] : (unsigned)nE;
    float a0 = hs[(size_t)r * 64 + lane];            // self-loop term
    float a1 = 0.f, a2 = 0.f, a3 = 0.f, a4 = 0.f, a5 = 0.f, a6 = 0.f, a7 = 0.f;
    for (unsigned e0 = beg; e0 < end; e0 += 64) {
        unsigned c = min(64u, end - e0);
        int sl = (lane < (int)c) ? perm[e0 + lane] : 0;   // coalesced edge read
        unsigned k = 0;
        for (; k + 8 <= c; k += 8) {
            int s0 = __shfl(sl, (int)k);
            int s1 = __shfl(sl, (int)k + 1);
            int s2 = __shfl(sl, (int)k + 2);
            int s3 = __shfl(sl, (int)k + 3);
            int s4 = __shfl(sl, (int)k + 4);
            int s5 = __shfl(sl, (int)k + 5);
            int s6 = __shfl(sl, (int)k + 6);
            int s7 = __shfl(sl, (int)k + 7);
            float v0 = hs[(size_t)s0 * 64 + lane];
            float v1 = hs[(size_t)s1 * 64 + lane];
            float v2 = hs[(size_t)s2 * 64 + lane];
            float v3 = hs[(size_t)s3 * 64 + lane];
            float v4 = hs[(size_t)s4 * 64 + lane];
            float v5 = hs[(size_t)s5 * 64 + lane];
            float v6 = hs[(size_t)s6 * 64 + lane];
            float v7 = hs[(size_t)s7 * 64 + lane];
            a0 += v0; a1 += v1; a2 += v2; a3 += v3;
            a4 += v4; a5 += v5; a6 += v6; a7 += v7;
        }
        for (; k + 4 <= c; k += 4) {
            int s0 = __shfl(sl, (int)k);
            int s1 = __shfl(sl, (int)k + 1);
            int s2 = __shfl(sl, (int)k + 2);
            int s3 = __shfl(sl, (int)k + 3);
            float v0 = hs[(size_t)s0 * 64 + lane];
            float v1 = hs[(size_t)s1 * 64 + lane];
            float v2 = hs[(size_t)s2 * 64 + lane];
            float v3 = hs[(size_t)s3 * 64 + lane];
            a0 += v0; a1 += v1; a2 += v2; a3 += v3;
        }
        for (; k < c; ++k) {
            int s = __shfl(sl, (int)k);
            a0 += hs[(size_t)s * 64 + lane];
        }
    }
    float acc = ((a0 + a1) + (a2 + a3)) + ((a4 + a5) + (a6 + a7));
    if (FIN) acc *= dinv[r];
    outb[(size_t)r * 64 + lane] = acc;
}

// ---------------------------------------------------------------------------
extern "C" void kernel_launch(void* const* d_in, const int* in_sizes, int n_in,
                              void* d_out, int out_size, void* d_ws, size_t ws_size,
                              hipStream_t stream) {
    const float* x  = (const float*)d_in[0];
    const int*   ei = (const int*)d_in[1];
    const float* W1 = (const float*)d_in[2];
    const float* W2 = (const float*)d_in[3];
    float* out = (float*)d_out;

    int n  = in_sizes[0] / IN_DIM;   // 100000
    int nE = in_sizes[1] / 2;        // 1600000
    const int* src = ei;
    const int* dst = ei + nE;

    // workspace carve-up (256B-aligned); d_out doubles as the layer-1 agg buffer
    char* w = (char*)d_ws;
    size_t nAl = ((size_t)n * 4 + 255) & ~(size_t)255;
    float*          dinv     = (float*)w;          w += nAl;
    unsigned*       cnt      = (unsigned*)w;       w += nAl;
    unsigned*       offs     = (unsigned*)w;       w += nAl;
    unsigned*       partials = (unsigned*)w;       w += 4096;
    unsigned short* rank     = (unsigned short*)w; w += ((size_t)nE * 2 + 255) & ~(size_t)255;
    int*            perm     = (int*)w;            w += ((size_t)nE * 4 + 255) & ~(size_t)255;
    float*          hs       = (float*)w;          w += (size_t)n * 64 * 4;
    float*          agg      = out;                // layer-1 aggregate lives in d_out

    int nb    = (n + SCAN_CHUNK - 1) / SCAN_CHUNK;
    int gE    = (nE + 255) / 256;
    int gN    = (n + 255) / 256;
    int gRow  = (n + 3) / 4;
    int gTile = (n + 31) / 32;

    // --- prologue: degrees + per-edge ranks, node offsets ---
    k_zero<<<gN, 256, 0, stream>>>(cnt, n);
    k_hist2<<<gE, 256, 0, stream>>>(dst, cnt, rank, nE);
    k_scanA<<<nb, 256, 0, stream>>>(cnt, offs, partials, dinv, n);
    k_scanB<<<1, 256, 0, stream>>>(partials, nb);
    k_scanC<<<gN, 256, 0, stream>>>(offs, partials, n);

    // --- layer 1 ---
    k_lin<IN_DIM, false><<<gTile, 512, 0, stream>>>(x, W1, dinv, hs, n);
    k_scat<<<gE, 256, 0, stream>>>(src, dst, rank, offs, perm, nE);
    k_gather<false><<<gRow, 256, 0, stream>>>(hs, offs, perm, dinv, agg, n, nE);

    // --- layer 2 (reuse hs for hs2; final dinv folded into gather) ---
    k_lin<OUT_DIM, true><<<gTile, 512, 0, stream>>>(agg, W2, dinv, hs, n);
    k_gather<true><<<gRow, 256, 0, stream>>>(hs, offs, perm, dinv, out, n, nE);
}